// Round 8
// baseline (331.419 us; speedup 1.0000x reference)
//
#include <hip/hip_runtime.h>
#include <math.h>
#include <stdint.h>

typedef __bf16 bf16x8 __attribute__((ext_vector_type(8)));
typedef float f32x4 __attribute__((ext_vector_type(4)));

#define TWO_PI_F 6.28318530717958647692f
#define INV_4PI_F 0.079577471545947667884f

// ---------------------------------------------------------------------------
// Stream-ordered packed-weight layout: 176 contiguous 16KB chunks in exact
// consumption order (phase t at ws + t*8192 bf16 elems):
//   0..63 W1F (k-order INTERLEAVED: k'=2c -> feature c (sin), k'=2c+1 ->
//              feature 1024+c (cos), so one trig-arg serves a sin/cos pair)
//   64..71 W2F | 72..79 W3F | 80..87 W4F
//   88..95 W4B | 96..103 W3B | 104..111 W2B
//   112..175 W1B (col c,c+1024 pairs per chunk)
// h-stash (NT=2 path) lives after the weights at H_OFF.
// ---------------------------------------------------------------------------
#define NPHASE 176
#define S_W2F 524288
#define S_W1B 917504
#define H_OFF 1441792ll            // 176*8192 bf16 elems (end of weights)
#define H_STRIDE 16777216ll        // 65536*256 bf16 elems per stashed layer

// k_prep geometry: 88 transpose blocks (fwd layouts, coalesced) +
// 352 gather blocks (bwd layouts, already 32B-contiguous per thread).
#define TPOSE_BLOCKS 88            // 64 W1F + 8 W2F + 8 W3F + 8 W4F
#define GATHER_CHUNKS 90112        // 65536 W1B + 3*8192 bwd
#define PREP_BLOCKS (TPOSE_BLOCKS + GATHER_CHUNKS / 256)   // 88 + 352 = 440

// async global->LDS, 16B per lane (global_load_lds_dwordx4)
typedef __attribute__((address_space(1))) const unsigned int GU32;
typedef __attribute__((address_space(3))) unsigned int LU32;
__device__ __forceinline__ void gll16(const __bf16* g, __bf16* l) {
  __builtin_amdgcn_global_load_lds((GU32*)(uintptr_t)(const void*)g,
                                   (LU32*)(unsigned int)(uintptr_t)(void*)l,
                                   16, 0, 0);
}

// ---------------------------------------------------------------------------
// Pack kernel, round 8: forward layouts via coalesced LDS-transpose tiles
// (was: 8 scattered 4B reads at 1KB stride per thread -> latency-bound,
//  ~30us); backward layouts keep the contiguous gather path.
// ---------------------------------------------------------------------------
__launch_bounds__(256)
__global__ void k_prep(const float* __restrict__ W1, const float* __restrict__ W2,
                       const float* __restrict__ W3, const float* __restrict__ W4,
                       __bf16* __restrict__ ws) {
  const int b = blockIdx.x;
  const int tid = threadIdx.x;

  if (b < TPOSE_BLOCKS) {
    // ---- transpose path: one 32-row x 256-col tile -> one 16KB chunk ----
    __shared__ __bf16 sT[32][264];   // +8 bf16 pad: col reads hop 4 banks/row
    const float* W; long dstbase; bool ilv; int kc;
    if (b < 64) {                          // W1F tile kc
      W = W1; kc = b; dstbase = (long)kc * 8192; ilv = true;
    } else {                               // W2F/W3F/W4F tile
      int l = (b - 64) >> 3; kc = (b - 64) & 7;
      W = (l == 0) ? W2 : (l == 1) ? W3 : W4;
      dstbase = S_W2F + (long)l * 65536 + (long)kc * 8192;
      ilv = false;
    }
    // load: 8 threads/row, 32 floats (8x float4) each, fully coalesced
    int r0 = tid >> 3;                     // k'loc 0..31
    int c0 = (tid & 7) * 32;
    int kg = kc * 32 + r0;
    int row = ilv ? ((kg & 1) ? 1024 + (kg >> 1) : (kg >> 1)) : kg;
    const float4* src = (const float4*)(W + (size_t)row * 256 + c0);
    #pragma unroll
    for (int i = 0; i < 8; ++i) {
      float4 v4 = src[i];
      int col = c0 + i * 4;
      sT[r0][col + 0] = (__bf16)v4.x; sT[r0][col + 1] = (__bf16)v4.y;
      sT[r0][col + 2] = (__bf16)v4.z; sT[r0][col + 3] = (__bf16)v4.w;
    }
    __syncthreads();
    // emit: 4 chunks/thread, 64B contiguous stores
    #pragma unroll
    for (int u = 0; u < 4; ++u) {
      int cl = tid * 4 + u;                // local chunk 0..1023
      int n = cl & 15, q = (cl >> 4) & 3, ct = cl >> 6;
      bf16x8 v;
      #pragma unroll
      for (int j = 0; j < 8; ++j) v[j] = sT[q * 8 + j][ct * 16 + n];
      *(bf16x8*)(ws + dstbase + (long)cl * 8) = v;
    }
    return;
  }

  // ---- gather path: bwd layouts, per-thread 32B-contiguous source ----
  int gid = (b - TPOSE_BLOCKS) * 256 + tid;
  const float* W; int n, q, ct, kc; long dstoff;
  if (gid < 65536) {                       // W1B: K=256, N=2048
    int c = gid; n = c & 15; q = (c >> 4) & 3; kc = (c >> 6) & 7; ct = c >> 9;
    int newct = ((ct & 63) << 1) | (ct >> 6);   // col-pair interleave
    long newc = (((long)newct * 8 + kc) * 4 + q) * 16 + n;
    W = W1; dstoff = S_W1B + newc * 8;
  } else {                                 // W2B/W3B/W4B
    int g = gid - 65536; int l = g >> 13; int c = g & 8191;
    n = c & 15; q = (c >> 4) & 3; ct = (c >> 6) & 15; kc = c >> 10;
    W = (l == 0) ? W2 : (l == 1) ? W3 : W4;
    dstoff = S_W2F + (long)(5 - l) * 65536 + (long)c * 8;
  }
  int k0 = kc * 32 + q * 8;
  int ngl = ct * 16 + n;
  bf16x8 v;
  #pragma unroll
  for (int j = 0; j < 8; ++j) v[j] = (__bf16)W[(size_t)ngl * 256 + k0 + j];
  *(bf16x8*)(ws + dstoff) = v;
}

// ---------------------------------------------------------------------------
// Fused MLP fwd + input-grad bwd + Biot-Savart tail. (byte-identical to the
// validated round-7 kernel)
// NT=2: 32 rows/wave, 128 rows/block, grid 512. Single-barrier DMA-dbuf
// weight stream. Tail: block's 128 rows = 128 Biot points; bdry staged into
// dead sW, partials + df-stash in dead sConv; writes alpha AND current.
// ---------------------------------------------------------------------------
template <int NT>
__launch_bounds__(256, 2)
__global__ void k_mlp(const float* __restrict__ x, const float* __restrict__ Brff,
                      const float* __restrict__ bdry,
                      const float* __restrict__ b1, const float* __restrict__ b2,
                      const float* __restrict__ b3, const float* __restrict__ b4,
                      const float* __restrict__ W5, const float* __restrict__ b5,
                      const __bf16* __restrict__ wsw, __bf16* __restrict__ hstash,
                      float* __restrict__ out, int N, int M) {
  __shared__ __attribute__((aligned(16))) __bf16 sW[2][8192];   // 32KB dbuf
  __shared__ __attribute__((aligned(16))) __bf16 sConv[16384];  // 8KB/wave conv
  __shared__ __attribute__((aligned(16))) float  sBr[3072];     // 12KB RFF

  const int tid  = threadIdx.x;
  const int wave = tid >> 6;
  const int lane = tid & 63;
  const int ml   = lane & 15;
  const int quad = lane >> 4;
  const int ROWS = 64 * NT;
  const int rowbase = blockIdx.x * ROWS + wave * (16 * NT);
  const int gw = blockIdx.x * 4 + wave;

  __bf16* conv = sConv + wave * 4096;

  auto ISSUE = [&](int t) {   // stage chunk t into sW[t&1] via async DMA
    if (t >= NPHASE) return;
    const __bf16* src = wsw + (size_t)t * 8192;
    __bf16* dst = &sW[t & 1][0];
    #pragma unroll
    for (int r = 0; r < 4; ++r) {
      int idx = tid + r * 256;
      gll16(src + (size_t)idx * 8, dst + idx * 8);
    }
  };

  // ---- prologue: Brff -> LDS, x -> regs, kick chunk 0 ----
  float4 bt0 = ((const float4*)Brff)[tid];
  float4 bt1 = ((const float4*)Brff)[tid + 256];
  float4 bt2 = ((const float4*)Brff)[tid + 512];

  float xa[NT][3];
  #pragma unroll
  for (int t = 0; t < NT; ++t) {
    const float* xp = x + (size_t)(rowbase + t * 16 + ml) * 3;
    #pragma unroll
    for (int i = 0; i < 3; ++i) xa[t][i] = fminf(fmaxf(xp[i], -1.f), 1.f);
  }

  ISSUE(0);
  ((float4*)sBr)[tid]       = bt0;
  ((float4*)sBr)[tid + 256] = bt1;
  ((float4*)sBr)[tid + 512] = bt2;

  f32x4 acc[NT][16];
  bf16x8 afr[NT][8];                 // current-layer A-frags (doubles as gf)
  bf16x8 h1f[8], h2f[8], h3f[8];     // only used when NT==1

  auto zero_acc = [&]() {
    #pragma unroll
    for (int t = 0; t < NT; ++t)
      #pragma unroll
      for (int ct = 0; ct < 16; ++ct) { f32x4 z = {0.f, 0.f, 0.f, 0.f}; acc[t][ct] = z; }
  };
  auto conv_widx = [&](int ct, int r) -> int {
    return (((ct >> 1) * 4 + ((ct & 1) << 1) + (ml >> 3)) * 16 + quad * 4 + r) * 8 + (ml & 7);
  };

  __syncthreads();   // chunk 0 + sBr resident

  // ---- Forward L1: y(RFF) @ W1, phases 0..63 (sin/cos pair-interleaved k) ----
  zero_acc();
  for (int kc = 0; kc < 64; ++kc) {
    ISSUE(kc + 1);
    int cb = kc * 16 + quad * 4;     // 4 trig args per phase, each -> sin+cos pair
    bf16x8 af[NT];
    #pragma unroll
    for (int i = 0; i < 4; ++i) {
      int c = cb + i;
      float w0 = sBr[c], w1 = sBr[1024 + c], w2 = sBr[2048 + c];
      #pragma unroll
      for (int t = 0; t < NT; ++t) {
        float tt = xa[t][0] * w0 + xa[t][1] * w1 + xa[t][2] * w2;
        float tf = __builtin_amdgcn_fractf(tt);
        af[t][2 * i]     = (__bf16)__builtin_amdgcn_sinf(tf);
        af[t][2 * i + 1] = (__bf16)__builtin_amdgcn_cosf(tf);
      }
    }
    const __bf16* wb = &sW[kc & 1][0];
    #pragma unroll
    for (int ct = 0; ct < 16; ++ct) {
      bf16x8 bfr = *(const bf16x8*)(wb + (ct * 4 + quad) * 128 + ml * 8);
      #pragma unroll
      for (int t = 0; t < NT; ++t)
        acc[t][ct] = __builtin_amdgcn_mfma_f32_16x16x32_bf16(af[t], bfr, acc[t][ct], 0, 0, 0);
    }
    __syncthreads();
  }

  // softplus(acc)+bias -> conv -> afr (A-frags); keep/stash h for backward
  auto epilogue_h = [&](const float* __restrict__ bias, bf16x8* keep, int l) {
    #pragma unroll
    for (int t = 0; t < NT; ++t) {
      #pragma unroll
      for (int ct = 0; ct < 16; ++ct) {
        float bcol = bias[ct * 16 + ml];
        #pragma unroll
        for (int r = 0; r < 4; ++r) {
          float z = acc[t][ct][r] + bcol;
          float h = fmaxf(z, 0.f) + __logf(1.f + __expf(-fabsf(z)));  // softplus
          conv[conv_widx(ct, r)] = (__bf16)h;
        }
      }
      #pragma unroll
      for (int ks = 0; ks < 8; ++ks)
        afr[t][ks] = *(const bf16x8*)(conv + (ks * 4 + quad) * 128 + ml * 8);
      if constexpr (NT == 2) {
        __bf16* hp = hstash + (size_t)l * H_STRIDE + (size_t)(gw * 2 + t) * 4096 + lane * 8;
        #pragma unroll
        for (int ks = 0; ks < 8; ++ks)
          *(bf16x8*)(hp + ks * 512) = afr[t][ks];
      }
    }
    if constexpr (NT == 1) {
      #pragma unroll
      for (int ks = 0; ks < 8; ++ks) keep[ks] = afr[0][ks];
    }
  };

  // K=256,N=256 GEMM over phases t0..t0+7 (input afr); single barrier/phase
  auto gemm256 = [&](int t0) {
    zero_acc();
    #pragma unroll
    for (int kc = 0; kc < 8; ++kc) {
      ISSUE(t0 + kc + 1);
      const __bf16* wb = &sW[(t0 + kc) & 1][0];
      #pragma unroll
      for (int ct = 0; ct < 16; ++ct) {
        bf16x8 bfr = *(const bf16x8*)(wb + (ct * 4 + quad) * 128 + ml * 8);
        #pragma unroll
        for (int t = 0; t < NT; ++t)
          acc[t][ct] = __builtin_amdgcn_mfma_f32_16x16x32_bf16(afr[t][kc], bfr, acc[t][ct], 0, 0, 0);
      }
      __syncthreads();
    }
  };

  epilogue_h(b1, h1f, 0);
  gemm256(64);               // W2F
  epilogue_h(b2, h2f, 1);
  gemm256(72);               // W3F
  epilogue_h(b3, h3f, 2);
  gemm256(80);               // W4F

  // ---- L4 epilogue: f head + g4 = sigma(z4)*W5 into afr ----
  {
    float fpart[NT][4];
    #pragma unroll
    for (int t = 0; t < NT; ++t)
      #pragma unroll
      for (int r = 0; r < 4; ++r) fpart[t][r] = 0.f;
    #pragma unroll
    for (int t = 0; t < NT; ++t) {
      #pragma unroll
      for (int ct = 0; ct < 16; ++ct) {
        float bcol = b4[ct * 16 + ml];
        float w5   = W5[ct * 16 + ml];
        #pragma unroll
        for (int r = 0; r < 4; ++r) {
          float z = acc[t][ct][r] + bcol;
          float ez = __expf(-fabsf(z));
          float sp = fmaxf(z, 0.f) + __logf(1.f + ez);
          float sig = (z >= 0.f) ? 1.f / (1.f + ez) : ez / (1.f + ez);
          fpart[t][r] += sp * w5;
          conv[conv_widx(ct, r)] = (__bf16)(sig * w5);
        }
      }
      #pragma unroll
      for (int r = 0; r < 4; ++r) {
        float v = fpart[t][r];
        #pragma unroll
        for (int m = 1; m < 16; m <<= 1) v += __shfl_xor(v, m, 64);
        if (ml == 0) out[rowbase + t * 16 + quad * 4 + r] = v + b5[0];
      }
      #pragma unroll
      for (int ks = 0; ks < 8; ++ks)
        afr[t][ks] = *(const bf16x8*)(conv + (ks * 4 + quad) * 128 + ml * 8);
    }
  }

  // ---- Backward: g_{l-1} = (g_l @ W_l^T) * (1 - exp(-h_{l-1})) ----
  auto epilogue_g = [&](const bf16x8* keep, int l) {
    #pragma unroll
    for (int t = 0; t < NT; ++t) {
      bf16x8 hv[8];
      if constexpr (NT == 2) {   // issue the h reloads first (latency overlap)
        const __bf16* hp = hstash + (size_t)l * H_STRIDE + (size_t)(gw * 2 + t) * 4096 + lane * 8;
        #pragma unroll
        for (int ks = 0; ks < 8; ++ks) hv[ks] = *(const bf16x8*)(hp + ks * 512);
      }
      #pragma unroll
      for (int ct = 0; ct < 16; ++ct)
        #pragma unroll
        for (int r = 0; r < 4; ++r) conv[conv_widx(ct, r)] = (__bf16)acc[t][ct][r];
      #pragma unroll
      for (int ks = 0; ks < 8; ++ks) {
        bf16x8 g = *(const bf16x8*)(conv + (ks * 4 + quad) * 128 + ml * 8);
        bf16x8 o;
        #pragma unroll
        for (int j = 0; j < 8; ++j) {
          float gp = (float)g[j];
          float h  = (NT == 2) ? (float)hv[ks][j] : (float)keep[ks][j];
          o[j] = (__bf16)(gp * (1.f - __expf(-h)));
        }
        afr[t][ks] = o;
      }
    }
  };

  gemm256(88);  epilogue_g(h3f, 2);   // W4B
  gemm256(96);  epilogue_g(h2f, 1);   // W3B
  gemm256(104); epilogue_g(h1f, 0);   // W2B

  // ---- Backward L1: phases 112..175, cols paired (c, c+1024) per chunk ----
  float xr[NT][4][3];
  #pragma unroll
  for (int t = 0; t < NT; ++t)
    #pragma unroll
    for (int r = 0; r < 4; ++r) {
      const float* xp = x + (size_t)(rowbase + t * 16 + quad * 4 + r) * 3;
      #pragma unroll
      for (int i = 0; i < 3; ++i) xr[t][r][i] = fminf(fmaxf(xp[i], -1.f), 1.f);
    }
  float dxa[NT][4][3];
  #pragma unroll
  for (int t = 0; t < NT; ++t)
    #pragma unroll
    for (int r = 0; r < 4; ++r) { dxa[t][r][0] = 0.f; dxa[t][r][1] = 0.f; dxa[t][r][2] = 0.f; }

  for (int p = 0; p < 64; ++p) {
    int tp = 112 + p;
    ISSUE(tp + 1);
    const __bf16* wb = &sW[tp & 1][0];
    f32x4 aA[NT], aB[NT];
    #pragma unroll
    for (int t = 0; t < NT; ++t) {
      f32x4 z = {0.f, 0.f, 0.f, 0.f}; aA[t] = z; aB[t] = z;
    }
    #pragma unroll
    for (int ks = 0; ks < 8; ++ks) {
      bf16x8 bA = *(const bf16x8*)(wb + (ks * 4 + quad) * 128 + ml * 8);
      bf16x8 bB = *(const bf16x8*)(wb + 4096 + (ks * 4 + quad) * 128 + ml * 8);
      #pragma unroll
      for (int t = 0; t < NT; ++t) {
        aA[t] = __builtin_amdgcn_mfma_f32_16x16x32_bf16(afr[t][ks], bA, aA[t], 0, 0, 0);
        aB[t] = __builtin_amdgcn_mfma_f32_16x16x32_bf16(afr[t][ks], bB, aB[t], 0, 0, 0);
      }
    }
    int c = p * 16 + ml;
    float B0 = sBr[c], B1 = sBr[1024 + c], B2 = sBr[2048 + c];
    #pragma unroll
    for (int t = 0; t < NT; ++t) {
      #pragma unroll
      for (int r = 0; r < 4; ++r) {
        float tt = xr[t][r][0] * B0 + xr[t][r][1] * B1 + xr[t][r][2] * B2;
        float tf = __builtin_amdgcn_fractf(tt);
        float sn = __builtin_amdgcn_sinf(tf);
        float cs = __builtin_amdgcn_cosf(tf);
        float dp = aA[t][r] * cs - aB[t][r] * sn;
        dxa[t][r][0] = fmaf(dp, B0, dxa[t][r][0]);
        dxa[t][r][1] = fmaf(dp, B1, dxa[t][r][1]);
        dxa[t][r][2] = fmaf(dp, B2, dxa[t][r][2]);
      }
    }
    __syncthreads();
  }

  // df writes (global) + df-stash to LDS for the tail's `current` computation
  float* dfsave = (float*)sConv + 1024;   // disjoint from red region
  #pragma unroll
  for (int t = 0; t < NT; ++t)
    #pragma unroll
    for (int r = 0; r < 4; ++r)
      #pragma unroll
      for (int i = 0; i < 3; ++i) {
        float v = dxa[t][r][i] * TWO_PI_F;
        #pragma unroll
        for (int m = 1; m < 16; m <<= 1) v += __shfl_xor(v, m, 64);
        if (ml == 0) {
          int lrow = wave * (16 * NT) + t * 16 + quad * 4 + r;
          out[(size_t)4 * N + (size_t)(blockIdx.x * ROWS + lrow) * 3 + i] = v;   // df
          dfsave[lrow * 3 + i] = v;
        }
      }

  // ---- Biot-Savart tail: this block's ROWS points ----
  {
    float* sb = (float*)sW;               // bdry stage (M*3 floats <= 8192)
    for (int i = tid; i < M * 3; i += 256) sb[i] = bdry[i];
    __syncthreads();                       // sb + dfsave visible

    const int GRP = 256 / ROWS;            // segment groups (NT=2: 2)
    const int segs = M / GRP;
    int pt = tid % ROWS, g = tid / ROWS;
    int row = blockIdx.x * ROWS + pt;
    const float* xp = x + (size_t)row * 3;
    float x0 = fminf(fmaxf(xp[0], -1.f), 1.f);
    float x1 = fminf(fmaxf(xp[1], -1.f), 1.f);
    float x2 = fminf(fmaxf(xp[2], -1.f), 1.f);
    float a0 = 0.f, a1 = 0.f, a2 = 0.f;
    for (int it = 0; it < segs; ++it) {
      int s = g * segs + it;
      int s1 = (s + 1 == M) ? 0 : s + 1;
      float b0 = sb[s * 3 + 0], b1v = sb[s * 3 + 1], b2v = sb[s * 3 + 2];
      float c0 = sb[s1 * 3 + 0], c1 = sb[s1 * 3 + 1], c2 = sb[s1 * 3 + 2];
      float e0 = c0 - b0, e1 = c1 - b1v, e2 = c2 - b2v;
      float d0 = x0 - 0.5f * (c0 + b0);
      float d1 = x1 - 0.5f * (c1 + b1v);
      float d2 = x2 - 0.5f * (c2 + b2v);
      float r2 = d0 * d0 + d1 * d1 + d2 * d2;
      float inv = rsqrtf(r2);
      float inv3 = inv * inv * inv;
      float n0 = e1 * d2 - e2 * d1;
      float n1 = e2 * d0 - e0 * d2;
      float n2 = e0 * d1 - e1 * d0;
      a0 = fmaf(n0, inv3, a0); a1 = fmaf(n1, inv3, a1); a2 = fmaf(n2, inv3, a2);
    }
    float* red = (float*)sConv;            // [0 .. (GRP-1)*ROWS*3)
    if (g) {
      float* rp = red + ((g - 1) * ROWS + pt) * 3;
      rp[0] = a0; rp[1] = a1; rp[2] = a2;
    }
    __syncthreads();
    if (g == 0) {
      #pragma unroll 4
      for (int q = 0; q < GRP - 1; ++q) {
        const float* rp = red + (q * ROWS + pt) * 3;
        a0 += rp[0]; a1 += rp[1]; a2 += rp[2];
      }
      a0 *= INV_4PI_F; a1 *= INV_4PI_F; a2 *= INV_4PI_F;
      float* alpha = out + (size_t)7 * N;
      alpha[(size_t)row * 3 + 0] = a0;
      alpha[(size_t)row * 3 + 1] = a1;
      alpha[(size_t)row * 3 + 2] = a2;
      const float* dfp = dfsave + pt * 3;
      out[(size_t)N + (size_t)row * 3 + 0] = dfp[0] + a0;   // current = df + alpha
      out[(size_t)N + (size_t)row * 3 + 1] = dfp[1] + a1;
      out[(size_t)N + (size_t)row * 3 + 2] = dfp[2] + a2;
    }
  }
}

extern "C" void kernel_launch(void* const* d_in, const int* in_sizes, int n_in,
                              void* d_out, int out_size, void* d_ws, size_t ws_size,
                              hipStream_t stream) {
  const float* x    = (const float*)d_in[0];
  const float* bdry = (const float*)d_in[1];
  const float* Brff = (const float*)d_in[2];
  const float* W1   = (const float*)d_in[3];
  const float* b1   = (const float*)d_in[4];
  const float* W2   = (const float*)d_in[5];
  const float* b2   = (const float*)d_in[6];
  const float* W3   = (const float*)d_in[7];
  const float* b3   = (const float*)d_in[8];
  const float* W4   = (const float*)d_in[9];
  const float* b4   = (const float*)d_in[10];
  const float* W5   = (const float*)d_in[11];
  const float* b5   = (const float*)d_in[12];
  float* out = (float*)d_out;
  __bf16* ws = (__bf16*)d_ws;
  int N = in_sizes[0] / 3;   // 65536
  int M = in_sizes[1] / 3;   // 512

  k_prep<<<PREP_BLOCKS, 256, 0, stream>>>(W1, W2, W3, W4, ws);

  size_t need = (size_t)(H_OFF + 3 * H_STRIDE) * sizeof(__bf16);  // ~103.5 MB
  if (ws_size >= need) {
    k_mlp<2><<<N / 128, 256, 0, stream>>>(x, Brff, bdry, b1, b2, b3, b4, W5, b5,
                                          ws, ws + H_OFF, out, N, M);
  } else {
    k_mlp<1><<<N / 64, 256, 0, stream>>>(x, Brff, bdry, b1, b2, b3, b4, W5, b5,
                                         ws, nullptr, out, N, M);
  }
}